// Round 4
// baseline (3010.060 us; speedup 1.0000x reference)
//
#include <hip/hip_runtime.h>
#include <hip/hip_bf16.h>
#include <math.h>

#define B_  64
#define T_  1024
#define H_  256
#define K_  64
#define U_  128
#define U3_ 384

#define LOG2E_F 1.4426950408889634f

typedef unsigned short ushort_t;
typedef __attribute__((ext_vector_type(8))) short short8;
typedef __attribute__((ext_vector_type(8))) _Float16 half8;
typedef __attribute__((ext_vector_type(4))) _Float16 half4v;
typedef __attribute__((ext_vector_type(4))) float floatx4;

__device__ __forceinline__ float bf2f(ushort_t v) {
  unsigned int u = ((unsigned int)v) << 16;
  return __builtin_bit_cast(float, u);
}
__device__ __forceinline__ float h2f(ushort_t v) {
  return (float)__builtin_bit_cast(_Float16, v);
}
__device__ __forceinline__ ushort_t f2h(float f) {
  return __builtin_bit_cast(ushort_t, (_Float16)f);
}
__device__ __forceinline__ float ldf(const void* p, size_t i, int isf) {
  return isf ? ((const float*)p)[i] : bf2f(((const ushort_t*)p)[i]);
}
// native exp2 (v_exp_f32); s_nop guards the trans->VALU hazard
__device__ __forceinline__ float exp2_hw(float x) {
  float r;
  asm volatile("v_exp_f32 %0, %1\n\ts_nop 0" : "=v"(r) : "v"(x));
  return r;
}
// pack 2 f32 -> 2 f16 (RTZ) in one instr
__device__ __forceinline__ unsigned pk2h(float a, float b) {
  unsigned r;
  asm("v_cvt_pkrtz_f16_f32 %0, %1, %2" : "=v"(r) : "v"(a), "v"(b));
  return r;
}
// tanh via exp2: 1 - 2/(e^{2x}+1)
__device__ __forceinline__ float tanh_fast(float x) {
  float E = exp2_hw(2.f * LOG2E_F * x);
  return 1.f - 2.f * __builtin_amdgcn_rcpf(E + 1.f);
}

// GRU gate quad: pre-scaled args (zr = -log2e*(xz|xr), ah/xh = 2*log2e*(...)).
__device__ __forceinline__ void gru_gate4(floatx4 az, floatx4 ar, floatx4 ah,
                                          uint4 zrv, uint2 hv, float4 ov,
                                          float* hs, float4& pend, uint2& wv,
                                          int addold) {
  half8 zr8 = __builtin_bit_cast(half8, zrv);
  half4v xh4 = __builtin_bit_cast(half4v, hv);
  float hn[4];
#pragma unroll
  for (int i = 0; i < 4; ++i) {
    float zq = (float)zr8[i] + az[i];
    float rq = (float)zr8[4 + i] + ar[i];
    float z = __builtin_amdgcn_rcpf(1.f + exp2_hw(zq));
    float rr = __builtin_amdgcn_rcpf(1.f + exp2_hw(rq));
    float y2 = fmaf(rr, ah[i], (float)xh4[i]);
    float th = fmaf(-2.f, __builtin_amdgcn_rcpf(exp2_hw(y2) + 1.f), 1.f);
    hn[i] = fmaf(z, hs[i] - th, th);
    hs[i] = hn[i];
  }
  pend.x = addold ? (ov.x + hn[0]) : hn[0];
  pend.y = addold ? (ov.y + hn[1]) : hn[1];
  pend.z = addold ? (ov.z + hn[2]) : hn[2];
  pend.w = addold ? (ov.w + hn[3]) : hn[3];
  wv.x = pk2h(hn[0], hn[1]);
  wv.y = pk2h(hn[2], hn[3]);
}

// ------------------------------------------------ dtype sniff: flag=1 if inputs are f32
__global__ void k_sniff(const ushort_t* __restrict__ xr, int* __restrict__ flag) {
  __shared__ int red[256];
  int tx = threadIdx.x;
  int hits = 0;
  for (int i = 0; i < 64; ++i) {
    ushort_t w = xr[tx + i * 256];
    int e = (w >> 7) & 0xff;
    hits += (e >= 0x70 && e <= 0x82) ? 1 : 0;
  }
  red[tx] = hits;
  __syncthreads();
  for (int off = 128; off > 0; off >>= 1) {
    if (tx < off) red[tx] += red[tx + off];
    __syncthreads();
  }
  if (tx == 0) flag[0] = (red[0] < 12288) ? 1 : 0;
}

// ------------------------------------------------ canonicalize x to f16 arena
__global__ __launch_bounds__(256) void k_canon_x(const void* __restrict__ xr,
                                                 const int* __restrict__ flag,
                                                 ushort_t* __restrict__ x16) {
  int tid = blockIdx.x * 256 + threadIdx.x;
  float v[8];
  if (*flag) {
    const float4* xf = (const float4*)xr;
    float4 a = xf[tid * 2], b = xf[tid * 2 + 1];
    v[0] = a.x; v[1] = a.y; v[2] = a.z; v[3] = a.w;
    v[4] = b.x; v[5] = b.y; v[6] = b.z; v[7] = b.w;
  } else {
    uint4 raw = ((const uint4*)xr)[tid];
    v[0] = bf2f((ushort_t)(raw.x & 0xffff)); v[1] = bf2f((ushort_t)(raw.x >> 16));
    v[2] = bf2f((ushort_t)(raw.y & 0xffff)); v[3] = bf2f((ushort_t)(raw.y >> 16));
    v[4] = bf2f((ushort_t)(raw.z & 0xffff)); v[5] = bf2f((ushort_t)(raw.z >> 16));
    v[6] = bf2f((ushort_t)(raw.w & 0xffff)); v[7] = bf2f((ushort_t)(raw.w >> 16));
  }
  uint4 o;
  o.x = (unsigned)f2h(v[0]) | ((unsigned)f2h(v[1]) << 16);
  o.y = (unsigned)f2h(v[2]) | ((unsigned)f2h(v[3]) << 16);
  o.z = (unsigned)f2h(v[4]) | ((unsigned)f2h(v[5]) << 16);
  o.w = (unsigned)f2h(v[6]) | ((unsigned)f2h(v[7]) << 16);
  ((uint4*)x16)[tid] = o;
}

// ------------------------------------------------ init m state
__global__ void k_init_m(const void* __restrict__ m0a, const void* __restrict__ m0o,
                         const int* __restrict__ flag,
                         float* __restrict__ ma_ws, float* __restrict__ mo_ws) {
  int b = blockIdx.x, tx = threadIdx.x, isf = *flag;
  ma_ws[b * H_ + tx] = ldf(m0a, tx, isf);
  mo_ws[b * H_ + tx] = ldf(m0o, tx, isf);
}

// ------------------------------------------------ Wt16[g][j][u] = W_g[u][j] * scale(j)
// scale = -log2e for z|r rows (j<256), +2*log2e for h rows (j>=256).
__global__ void k_transpose(const void* __restrict__ Wa, const void* __restrict__ Wo,
                            const int* __restrict__ flag, ushort_t* __restrict__ Wt16) {
  int bx = blockIdx.x, isf = *flag;
  int g = bx / 192;
  int i = (bx % 192) * 256 + threadIdx.x;  // i = j*128 + u
  const void* W = g ? Wo : Wa;
  int jj = i >> 7, u = i & 127;
  float sc = (jj < 256) ? -LOG2E_F : (2.f * LOG2E_F);
  Wt16[(size_t)g * (U3_ * U_) + i] = f2h(ldf(W, u * U3_ + jj, isf) * sc);
}

// ------------------------------------------------ Phase A: P16[b, g*64+k, h] = sum_j U[k,h,j] m[b,j]
__global__ __launch_bounds__(256) void k_phaseA(
    const void* __restrict__ Ua, const void* __restrict__ Va,
    const void* __restrict__ Uo, const void* __restrict__ Vo,
    const int* __restrict__ flag,
    const float* __restrict__ ma_ws, const float* __restrict__ mo_ws,
    ushort_t* __restrict__ P16) {
  int gk = blockIdx.x;
  int g = gk >> 6, k = gk & 63;
  const void* U = (g == 0) ? Ua : (g == 1) ? Va : (g == 2) ? Uo : Vo;
  const float* msrc = (g & 1) ? mo_ws : ma_ws;
  int tx = threadIdx.x;  // h
  int isf = *flag;
  __shared__ __align__(16) float m_l[64 * 128];
  float acc[64];
#pragma unroll
  for (int b = 0; b < 64; ++b) acc[b] = 0.f;
  size_t rowoff = ((size_t)k * H_ + tx) * H_;
  for (int pass = 0; pass < 2; ++pass) {
    for (int i = 0; i < 32; ++i) {
      int flat = tx + i * 256;
      m_l[flat] = msrc[(flat >> 7) * H_ + pass * 128 + (flat & 127)];
    }
    __syncthreads();
    for (int c = 0; c < 16; ++c) {
      float uv[8];
      if (isf) {
        const float* uf = (const float*)U + rowoff + pass * 128 + c * 8;
        float4 A = *(const float4*)uf;
        float4 Bv = *(const float4*)(uf + 4);
        uv[0] = A.x; uv[1] = A.y; uv[2] = A.z; uv[3] = A.w;
        uv[4] = Bv.x; uv[5] = Bv.y; uv[6] = Bv.z; uv[7] = Bv.w;
      } else {
        const ushort_t* ub = (const ushort_t*)U + rowoff + pass * 128 + c * 8;
        uint4 raw = *(const uint4*)ub;
        uv[0] = bf2f((ushort_t)(raw.x & 0xffff)); uv[1] = bf2f((ushort_t)(raw.x >> 16));
        uv[2] = bf2f((ushort_t)(raw.y & 0xffff)); uv[3] = bf2f((ushort_t)(raw.y >> 16));
        uv[4] = bf2f((ushort_t)(raw.z & 0xffff)); uv[5] = bf2f((ushort_t)(raw.z >> 16));
        uv[6] = bf2f((ushort_t)(raw.w & 0xffff)); uv[7] = bf2f((ushort_t)(raw.w >> 16));
      }
#pragma unroll
      for (int b = 0; b < 64; ++b) {
        const float* mr = &m_l[b * 128 + c * 8];
        float4 mA = *(const float4*)mr;
        float4 mB = *(const float4*)(mr + 4);
        float s = acc[b];
        s = fmaf(uv[0], mA.x, s); s = fmaf(uv[1], mA.y, s);
        s = fmaf(uv[2], mA.z, s); s = fmaf(uv[3], mA.w, s);
        s = fmaf(uv[4], mB.x, s); s = fmaf(uv[5], mB.y, s);
        s = fmaf(uv[6], mB.z, s); s = fmaf(uv[7], mB.w, s);
        acc[b] = s;
      }
    }
    __syncthreads();
  }
  size_t base = ((size_t)(g * 64 + k)) * H_ + tx;
#pragma unroll 4
  for (int b = 0; b < 64; ++b) P16[base + (size_t)b * (256 * H_)] = f2h(acc[b]);
}

// ------------------------------------------------ Phase B (MFMA f16): tanh(x[b]·P[b]^T)
__global__ __launch_bounds__(256) void k_phaseB(
    const ushort_t* __restrict__ x16, const ushort_t* __restrict__ P16,
    ushort_t* __restrict__ aspect, ushort_t* __restrict__ opinion) {
  int bx = blockIdx.x;          // 4096 = 64 b x 64 tt
  int b = bx >> 6, tt = bx & 63;
  int w = threadIdx.x >> 6;
  int lane = threadIdx.x & 63;
  int m = lane & 15, q = lane >> 4;
  const ushort_t* arow = x16 + ((size_t)(b * T_ + tt * 16 + m)) * H_ + q * 8;
  half8 af[8];
#pragma unroll
  for (int c = 0; c < 8; ++c)
    af[c] = __builtin_bit_cast(half8, *(const short8*)(arow + c * 32));
  const ushort_t* pbase = P16 + ((size_t)(b * 256 + m)) * H_ + q * 8;
#pragma unroll
  for (int s = 0; s < 4; ++s) {
    int ntile = s * 4 + w;
    const ushort_t* brow = pbase + (size_t)(ntile * 16) * H_;
    floatx4 acc = {0.f, 0.f, 0.f, 0.f}, acc2 = acc;
#pragma unroll
    for (int c = 0; c < 4; ++c) {
      half8 bf = __builtin_bit_cast(half8, *(const short8*)(brow + c * 32));
      acc = __builtin_amdgcn_mfma_f32_16x16x32_f16(af[c], bf, acc, 0, 0, 0);
      half8 bf2 = __builtin_bit_cast(half8, *(const short8*)(brow + (c + 4) * 32));
      acc2 = __builtin_amdgcn_mfma_f32_16x16x32_f16(af[c + 4], bf2, acc2, 0, 0, 0);
    }
    int n = ntile * 16 + m;
    ushort_t* dst;
    int nn;
    if (n < 128) { dst = aspect; nn = n; } else { dst = opinion; nn = n - 128; }
#pragma unroll
    for (int i = 0; i < 4; ++i) {
      int t = tt * 16 + q * 4 + i;
      dst[((size_t)(b * T_ + t)) * U_ + nn] = f2h(tanh_fast(acc[i] + acc2[i]));
    }
  }
}

// ------------------------------------------------ Phase C (MFMA f16): xw = seq @ Wt
// z|r cols interleaved per 4-col group so scan reads z+r as one uint4.
__global__ __launch_bounds__(256) void k_phaseC(
    const ushort_t* __restrict__ aspect, const ushort_t* __restrict__ opinion,
    const ushort_t* __restrict__ Wt16,
    ushort_t* __restrict__ zr_a, ushort_t* __restrict__ zr_o,
    ushort_t* __restrict__ xh_a, ushort_t* __restrict__ xh_o) {
  int g = blockIdx.y;
  const ushort_t* A = g ? opinion : aspect;
  const ushort_t* Bm = Wt16 + (size_t)g * (U3_ * U_);
  ushort_t* ZR = g ? zr_o : zr_a;
  ushort_t* XH = g ? xh_o : xh_a;
  int mt = blockIdx.x;
  int w = threadIdx.x >> 6;
  int lane = threadIdx.x & 63;
  int m = lane & 15, q = lane >> 4;
  const ushort_t* arow = A + ((size_t)(mt * 16 + m)) * U_ + q * 8;
  half8 af[4];
#pragma unroll
  for (int c = 0; c < 4; ++c)
    af[c] = __builtin_bit_cast(half8, *(const short8*)(arow + c * 32));
  const ushort_t* bbase = Bm + (size_t)m * U_ + q * 8;
#pragma unroll
  for (int s = 0; s < 6; ++s) {
    int nt = s * 4 + w;
    const ushort_t* brow = bbase + (size_t)(nt * 16) * U_;
    floatx4 acc = {0.f, 0.f, 0.f, 0.f};
#pragma unroll
    for (int c = 0; c < 4; ++c) {
      half8 bf = __builtin_bit_cast(half8, *(const short8*)(brow + c * 32));
      acc = __builtin_amdgcn_mfma_f32_16x16x32_f16(af[c], bf, acc, 0, 0, 0);
    }
    int col = nt * 16 + m;
    if (nt < 16) {
      int c2 = (col < 128) ? (((col >> 2) << 3) + (col & 3))
                           : ((((col - 128) >> 2) << 3) + 4 + (col & 3));
#pragma unroll
      for (int i = 0; i < 4; ++i) {
        int row = mt * 16 + q * 4 + i;
        ZR[(size_t)row * 256 + c2] = f2h(acc[i]);
      }
    } else {
#pragma unroll
      for (int i = 0; i < 4; ++i) {
        int row = mt * 16 + q * 4 + i;
        XH[(size_t)row * U_ + (col - 256)] = f2h(acc[i]);
      }
    }
  }
}

// ------------------------------------------------ GRU scan, MFMA-batched over b.
// v3: 4 waves x 64 (256 thr), 1 wave/SIMD. Wave w owns row-tiles {w, w+4} of
// each gate block (j in [16w,16w+16) u [64+16w, 64+16w+16)) -> halves the LDS
// read burst (16 ds_read_b128/CU/step) and removes the duplicated VALU phase.
// a+c accumulator merge folded into depth-4 C-chained MFMA (6 indep chains).
template <int LAYER>
__global__ __launch_bounds__(256, 1) void k_scan(
    const ushort_t* __restrict__ zr_a, const ushort_t* __restrict__ zr_o,
    const ushort_t* __restrict__ xh_a, const ushort_t* __restrict__ xh_o,
    const ushort_t* __restrict__ Rt16,
    float* __restrict__ out) {
  int g = blockIdx.x >> 2;
  int bb = (blockIdx.x & 3) << 4;
  int tid = threadIdx.x;
  int w = tid >> 6;    // wave 0..3
  int lane = tid & 63;
  int r = lane & 15;
  int q = lane >> 4;
  int b = bb + r;
  int j0 = (w << 4) + (q << 2);   // group-0 base j (group-1 = j0 + 64)

  const ushort_t* zr = g ? zr_o : zr_a;
  const ushort_t* xh = g ? xh_o : xh_a;
  const ushort_t* Rt = Rt16 + (size_t)g * (U3_ * U_);

  // af[jg][gate][ks] : Rt rows [128*gate + 64*jg + 16*w + r]
  half8 af[2][3][4];
#pragma unroll
  for (int jg = 0; jg < 2; ++jg)
#pragma unroll
    for (int gt = 0; gt < 3; ++gt) {
      size_t row = (size_t)(128 * gt + 64 * jg + 16 * w + r) * U_;
#pragma unroll
      for (int ks = 0; ks < 4; ++ks)
        af[jg][gt][ks] =
            __builtin_bit_cast(half8, *(const short8*)(Rt + row + ks * 32 + q * 8));
    }

  __shared__ __align__(16) ushort_t hbuf[4096];  // 2 x 4KB frag buffers
  ((uint4*)hbuf)[tid] = (uint4){0u, 0u, 0u, 0u}; // zero buffer 0 (256 thr x 16B)

  float hs0[4] = {0.f, 0.f, 0.f, 0.f};
  float hs1[4] = {0.f, 0.f, 0.f, 0.f};

  const ushort_t* zp = zr + (size_t)b * (T_ * 256) + j0 * 2;  // interleaved z|r
  const ushort_t* xp = xh + (size_t)b * (T_ * U_) + j0;
  float* op = out + ((size_t)g * B_ * T_ + (size_t)b * T_) * U_ + j0;

  uint4 zrA0 = *(const uint4*)zp;
  uint4 zrA1 = *(const uint4*)(zp + 128);
  uint4 zrB0 = *(const uint4*)(zp + 256);
  uint4 zrB1 = *(const uint4*)(zp + 256 + 128);
  uint2 hA0 = *(const uint2*)xp;
  uint2 hA1 = *(const uint2*)(xp + 64);
  uint2 hB0 = *(const uint2*)(xp + U_);
  uint2 hB1 = *(const uint2*)(xp + U_ + 64);
  float4 oA0 = make_float4(0.f, 0.f, 0.f, 0.f), oA1 = oA0, oB0 = oA0, oB1 = oA0;
  if (LAYER) {
    oA0 = *(const float4*)op;            oA1 = *(const float4*)(op + 64);
    oB0 = *(const float4*)(op + U_);     oB1 = *(const float4*)(op + U_ + 64);
  }
  float4 pendE0, pendE1, pendO0, pendO1;

  // write slot: addr(j,b) = (j>>5)*512 + ((j>>3)&3)*128 + b*8 + (j&7); jg1 = +1024
  int wof0 = ((j0 >> 5) << 9) + (((j0 >> 3) & 3) << 7) + (r << 3) + (j0 & 7);

  __syncthreads();

  for (int t = 0; t < T_; t += 2) {
    // ===== even step t : read buf0, write buf1
    {
      half8 bf0 = __builtin_bit_cast(half8, *(const short8*)(&hbuf[0 * 512 + lane * 8]));
      half8 bf1 = __builtin_bit_cast(half8, *(const short8*)(&hbuf[1 * 512 + lane * 8]));
      half8 bf2 = __builtin_bit_cast(half8, *(const short8*)(&hbuf[2 * 512 + lane * 8]));
      half8 bf3 = __builtin_bit_cast(half8, *(const short8*)(&hbuf[3 * 512 + lane * 8]));
      if (t != 0) {
        *(float4*)(op - U_) = pendO0;
        *(float4*)(op - U_ + 64) = pendO1;
      }
      int adv = (t + 2 < T_) ? 2 : 0;
      uint4 pz0 = *(const uint4*)(zp + adv * 256);
      uint4 pz1 = *(const uint4*)(zp + adv * 256 + 128);
      uint2 ph0 = *(const uint2*)(xp + adv * U_);
      uint2 ph1 = *(const uint2*)(xp + adv * U_ + 64);
      float4 po0, po1;
      if (LAYER) {
        po0 = *(const float4*)(op + adv * U_);
        po1 = *(const float4*)(op + adv * U_ + 64);
      }
      floatx4 zz = {0.f, 0.f, 0.f, 0.f};
      floatx4 az0 = __builtin_amdgcn_mfma_f32_16x16x32_f16(af[0][0][0], bf0,
                    __builtin_amdgcn_mfma_f32_16x16x32_f16(af[0][0][1], bf1,
                    __builtin_amdgcn_mfma_f32_16x16x32_f16(af[0][0][2], bf2,
                    __builtin_amdgcn_mfma_f32_16x16x32_f16(af[0][0][3], bf3, zz, 0,0,0), 0,0,0), 0,0,0), 0,0,0);
      floatx4 ar0 = __builtin_amdgcn_mfma_f32_16x16x32_f16(af[0][1][0], bf0,
                    __builtin_amdgcn_mfma_f32_16x16x32_f16(af[0][1][1], bf1,
                    __builtin_amdgcn_mfma_f32_16x16x32_f16(af[0][1][2], bf2,
                    __builtin_amdgcn_mfma_f32_16x16x32_f16(af[0][1][3], bf3, zz, 0,0,0), 0,0,0), 0,0,0), 0,0,0);
      floatx4 ah0 = __builtin_amdgcn_mfma_f32_16x16x32_f16(af[0][2][0], bf0,
                    __builtin_amdgcn_mfma_f32_16x16x32_f16(af[0][2][1], bf1,
                    __builtin_amdgcn_mfma_f32_16x16x32_f16(af[0][2][2], bf2,
                    __builtin_amdgcn_mfma_f32_16x16x32_f16(af[0][2][3], bf3, zz, 0,0,0), 0,0,0), 0,0,0), 0,0,0);
      floatx4 az1 = __builtin_amdgcn_mfma_f32_16x16x32_f16(af[1][0][0], bf0,
                    __builtin_amdgcn_mfma_f32_16x16x32_f16(af[1][0][1], bf1,
                    __builtin_amdgcn_mfma_f32_16x16x32_f16(af[1][0][2], bf2,
                    __builtin_amdgcn_mfma_f32_16x16x32_f16(af[1][0][3], bf3, zz, 0,0,0), 0,0,0), 0,0,0), 0,0,0);
      floatx4 ar1 = __builtin_amdgcn_mfma_f32_16x16x32_f16(af[1][1][0], bf0,
                    __builtin_amdgcn_mfma_f32_16x16x32_f16(af[1][1][1], bf1,
                    __builtin_amdgcn_mfma_f32_16x16x32_f16(af[1][1][2], bf2,
                    __builtin_amdgcn_mfma_f32_16x16x32_f16(af[1][1][3], bf3, zz, 0,0,0), 0,0,0), 0,0,0), 0,0,0);
      floatx4 ah1 = __builtin_amdgcn_mfma_f32_16x16x32_f16(af[1][2][0], bf0,
                    __builtin_amdgcn_mfma_f32_16x16x32_f16(af[1][2][1], bf1,
                    __builtin_amdgcn_mfma_f32_16x16x32_f16(af[1][2][2], bf2,
                    __builtin_amdgcn_mfma_f32_16x16x32_f16(af[1][2][3], bf3, zz, 0,0,0), 0,0,0), 0,0,0), 0,0,0);
      uint2 wv0, wv1;
      gru_gate4(az0, ar0, ah0, zrA0, hA0, oA0, hs0, pendE0, wv0, LAYER);
      gru_gate4(az1, ar1, ah1, zrA1, hA1, oA1, hs1, pendE1, wv1, LAYER);
      *(uint2*)(&hbuf[2048 + wof0]) = wv0;
      *(uint2*)(&hbuf[2048 + 1024 + wof0]) = wv1;
      zrA0 = pz0; zrA1 = pz1; hA0 = ph0; hA1 = ph1;
      if (LAYER) { oA0 = po0; oA1 = po1; }
    }
    asm volatile("s_waitcnt lgkmcnt(0)" ::: "memory");
    __builtin_amdgcn_s_barrier();
    __builtin_amdgcn_sched_barrier(0);
    // ===== odd step t+1 : read buf1, write buf0
    {
      half8 bf0 = __builtin_bit_cast(half8, *(const short8*)(&hbuf[2048 + 0 * 512 + lane * 8]));
      half8 bf1 = __builtin_bit_cast(half8, *(const short8*)(&hbuf[2048 + 1 * 512 + lane * 8]));
      half8 bf2 = __builtin_bit_cast(half8, *(const short8*)(&hbuf[2048 + 2 * 512 + lane * 8]));
      half8 bf3 = __builtin_bit_cast(half8, *(const short8*)(&hbuf[2048 + 3 * 512 + lane * 8]));
      *(float4*)op = pendE0;
      *(float4*)(op + 64) = pendE1;
      int adv = (t + 3 < T_) ? 2 : 0;
      uint4 pz0 = *(const uint4*)(zp + 256 + adv * 256);
      uint4 pz1 = *(const uint4*)(zp + 256 + adv * 256 + 128);
      uint2 ph0 = *(const uint2*)(xp + U_ + adv * U_);
      uint2 ph1 = *(const uint2*)(xp + U_ + adv * U_ + 64);
      float4 po0, po1;
      if (LAYER) {
        po0 = *(const float4*)(op + U_ + adv * U_);
        po1 = *(const float4*)(op + U_ + adv * U_ + 64);
      }
      floatx4 zz = {0.f, 0.f, 0.f, 0.f};
      floatx4 az0 = __builtin_amdgcn_mfma_f32_16x16x32_f16(af[0][0][0], bf0,
                    __builtin_amdgcn_mfma_f32_16x16x32_f16(af[0][0][1], bf1,
                    __builtin_amdgcn_mfma_f32_16x16x32_f16(af[0][0][2], bf2,
                    __builtin_amdgcn_mfma_f32_16x16x32_f16(af[0][0][3], bf3, zz, 0,0,0), 0,0,0), 0,0,0), 0,0,0);
      floatx4 ar0 = __builtin_amdgcn_mfma_f32_16x16x32_f16(af[0][1][0], bf0,
                    __builtin_amdgcn_mfma_f32_16x16x32_f16(af[0][1][1], bf1,
                    __builtin_amdgcn_mfma_f32_16x16x32_f16(af[0][1][2], bf2,
                    __builtin_amdgcn_mfma_f32_16x16x32_f16(af[0][1][3], bf3, zz, 0,0,0), 0,0,0), 0,0,0), 0,0,0);
      floatx4 ah0 = __builtin_amdgcn_mfma_f32_16x16x32_f16(af[0][2][0], bf0,
                    __builtin_amdgcn_mfma_f32_16x16x32_f16(af[0][2][1], bf1,
                    __builtin_amdgcn_mfma_f32_16x16x32_f16(af[0][2][2], bf2,
                    __builtin_amdgcn_mfma_f32_16x16x32_f16(af[0][2][3], bf3, zz, 0,0,0), 0,0,0), 0,0,0), 0,0,0);
      floatx4 az1 = __builtin_amdgcn_mfma_f32_16x16x32_f16(af[1][0][0], bf0,
                    __builtin_amdgcn_mfma_f32_16x16x32_f16(af[1][0][1], bf1,
                    __builtin_amdgcn_mfma_f32_16x16x32_f16(af[1][0][2], bf2,
                    __builtin_amdgcn_mfma_f32_16x16x32_f16(af[1][0][3], bf3, zz, 0,0,0), 0,0,0), 0,0,0), 0,0,0);
      floatx4 ar1 = __builtin_amdgcn_mfma_f32_16x16x32_f16(af[1][1][0], bf0,
                    __builtin_amdgcn_mfma_f32_16x16x32_f16(af[1][1][1], bf1,
                    __builtin_amdgcn_mfma_f32_16x16x32_f16(af[1][1][2], bf2,
                    __builtin_amdgcn_mfma_f32_16x16x32_f16(af[1][1][3], bf3, zz, 0,0,0), 0,0,0), 0,0,0), 0,0,0);
      floatx4 ah1 = __builtin_amdgcn_mfma_f32_16x16x32_f16(af[1][2][0], bf0,
                    __builtin_amdgcn_mfma_f32_16x16x32_f16(af[1][2][1], bf1,
                    __builtin_amdgcn_mfma_f32_16x16x32_f16(af[1][2][2], bf2,
                    __builtin_amdgcn_mfma_f32_16x16x32_f16(af[1][2][3], bf3, zz, 0,0,0), 0,0,0), 0,0,0), 0,0,0);
      uint2 wv0, wv1;
      gru_gate4(az0, ar0, ah0, zrB0, hB0, oB0, hs0, pendO0, wv0, LAYER);
      gru_gate4(az1, ar1, ah1, zrB1, hB1, oB1, hs1, pendO1, wv1, LAYER);
      *(uint2*)(&hbuf[0 + wof0]) = wv0;
      *(uint2*)(&hbuf[1024 + wof0]) = wv1;
      zrB0 = pz0; zrB1 = pz1; hB0 = ph0; hB1 = ph1;
      if (LAYER) { oB0 = po0; oB1 = po1; }
    }
    asm volatile("s_waitcnt lgkmcnt(0)" ::: "memory");
    __builtin_amdgcn_s_barrier();
    __builtin_amdgcn_sched_barrier(0);
    zp += 512; xp += 2 * U_; op += 2 * U_;
  }
  *(float4*)(op - U_) = pendO0;       // final step T-1
  *(float4*)(op - U_ + 64) = pendO1;
}

// ------------------------------------------------ scores[g,b,t] = ra[b,t,:]·v
__global__ void k_score(const float* __restrict__ out, const void* __restrict__ va,
                        const void* __restrict__ vo, const int* __restrict__ flag,
                        float* __restrict__ scores) {
  int wave = threadIdx.x >> 6, lane = threadIdx.x & 63;
  int pair = blockIdx.x * 4 + wave;
  int g = pair >> 16;
  int bt = pair & 65535;
  int isf = *flag;
  const void* v = g ? vo : va;
  const float* o = out + ((size_t)g * (B_ * T_) + bt) * U_ + lane * 2;
  float s = o[0] * ldf(v, lane * 2, isf) + o[1] * ldf(v, lane * 2 + 1, isf);
#pragma unroll
  for (int off = 32; off > 0; off >>= 1) s += __shfl_down(s, off, 64);
  if (lane == 0) scores[pair] = s;
}

// ------------------------------------------------ softmax over T, in place
__global__ void k_softmax(float* __restrict__ scores) {
  int row = blockIdx.x;
  float* s = scores + (size_t)row * T_;
  int tx = threadIdx.x;
  __shared__ float red[256];
  float v[4];
  float mx = -1e30f;
#pragma unroll
  for (int i = 0; i < 4; ++i) { v[i] = s[tx + i * 256]; mx = fmaxf(mx, v[i]); }
  red[tx] = mx;
  __syncthreads();
  for (int off = 128; off > 0; off >>= 1) {
    if (tx < off) red[tx] = fmaxf(red[tx], red[tx + off]);
    __syncthreads();
  }
  float M = red[0];
  __syncthreads();
  float sm = 0.f;
#pragma unroll
  for (int i = 0; i < 4; ++i) { v[i] = expf(v[i] - M); sm += v[i]; }
  red[tx] = sm;
  __syncthreads();
  for (int off = 128; off > 0; off >>= 1) {
    if (tx < off) red[tx] += red[tx + off];
    __syncthreads();
  }
  float inv = 1.f / red[0];
#pragma unroll
  for (int i = 0; i < 4; ++i) s[tx + i * 256] = v[i] * inv;
}

// ------------------------------------------------ m = tanh(m@M) + alpha^T x  (4-way t-parallel)
__global__ __launch_bounds__(1024) void k_ctx_m(const float* __restrict__ alpha,
                                                const void* __restrict__ x,
                                                const void* __restrict__ Ma,
                                                const void* __restrict__ Mo,
                                                const int* __restrict__ flag,
                                                float* __restrict__ ma_ws,
                                                float* __restrict__ mo_ws) {
  int g = blockIdx.x >> 6, b = blockIdx.x & 63;
  int isf = *flag;
  int tid = threadIdx.x;
  int tx = tid & 255;
  int ty = tid >> 8;
  __shared__ float a_l[1024];
  __shared__ float m_l[256];
  __shared__ float pA[4][256];
  __shared__ float pB[4][256];
  const float* al = alpha + ((size_t)g * B_ + b) * T_;
  a_l[tid] = al[tid];
  if (ty == 0) m_l[tx] = (g ? mo_ws : ma_ws)[b * H_ + tx];
  __syncthreads();
  const void* Mm = g ? Mo : Ma;
  float acc = 0.f;
#pragma unroll 4
  for (int t0 = 0; t0 < 256; ++t0) {
    int t = ty * 256 + t0;
    acc = fmaf(a_l[t], ldf(x, (size_t)(b * T_ + t) * H_ + tx, isf), acc);
  }
  float acc2 = 0.f;
#pragma unroll 4
  for (int c = 0; c < 64; ++c) {
    int jj = ty * 64 + c;
    acc2 = fmaf(m_l[jj], ldf(Mm, (size_t)jj * 256 + tx, isf), acc2);
  }
  pA[ty][tx] = acc;
  pB[ty][tx] = acc2;
  __syncthreads();
  if (ty == 0) {
    float A = pA[0][tx] + pA[1][tx] + pA[2][tx] + pA[3][tx];
    float Bv = pB[0][tx] + pB[1][tx] + pB[2][tx] + pB[3][tx];
    float* m_ws = g ? mo_ws : ma_ws;
    m_ws[b * H_ + tx] = tanhf(Bv) + A;
  }
}

// ------------------------------------------------ launch
extern "C" void kernel_launch(void* const* d_in, const int* in_sizes, int n_in,
                              void* d_out, int out_size, void* d_ws, size_t ws_size,
                              hipStream_t stream) {
  const void* x_r = d_in[0];
  const void* m0a = d_in[1];
  const void* m0o = d_in[2];
  const void* Ua  = d_in[3];
  const void* Uo  = d_in[4];
  const void* Va  = d_in[5];
  const void* Vo  = d_in[6];
  const void* Ma  = d_in[7];
  const void* Mo  = d_in[8];
  const void* va  = d_in[9];
  const void* vo  = d_in[10];
  const void* Wa  = d_in[11];
  const void* Ra  = d_in[12];
  const void* Wo  = d_in[13];
  const void* Ro  = d_in[14];
  float* out = (float*)d_out;

  char* ws = (char*)d_ws;
  int*      flag    = (int*)(ws + 0);                // 1 KB pad
  float*    ma_ws   = (float*)(ws + 1024);           // 64 KB
  float*    mo_ws   = (float*)(ws + 66560);          // 64 KB
  ushort_t* Wt16    = (ushort_t*)(ws + 132096);      // 192 KB [2,384,128] f16, pre-scaled
  ushort_t* x16     = (ushort_t*)(ws + 328704);      // 32 MB  [64,1024,256] f16
  ushort_t* P16     = (ushort_t*)(ws + 33883136);    // 8 MB   [64,256,256] f16
  float*    scores  = (float*)(ws + 33883136);       // ALIAS: P16 dead while scores live
  ushort_t* Rt16    = (ushort_t*)(ws + 33883136 + 1048576);  // ALIAS in P16 region @+1MB
  ushort_t* aspect  = (ushort_t*)(ws + 42271744);    // 16 MB
  ushort_t* opinion = (ushort_t*)(ws + 59048960);    // 16 MB
  ushort_t* zr_a    = (ushort_t*)(ws + 75826176);    // 32 MB (z|r interleaved per 4-col)
  ushort_t* zr_o    = (ushort_t*)(ws + 109380608);   // 32 MB
  ushort_t* xh_a    = (ushort_t*)(ws + 142935040);   // 16 MB
  ushort_t* xh_o    = (ushort_t*)(ws + 159712256);   // 16 MB -> total 176,489,472 B

  if (ws_size < 176489472ULL) return;

  k_sniff<<<dim3(1), dim3(256), 0, stream>>>((const ushort_t*)x_r, flag);
  k_canon_x<<<dim3(8192), dim3(256), 0, stream>>>(x_r, flag, x16);
  k_init_m<<<dim3(64), dim3(256), 0, stream>>>(m0a, m0o, flag, ma_ws, mo_ws);
  k_transpose<<<dim3(384), dim3(256), 0, stream>>>(Wa, Wo, flag, Wt16);

  for (int layer = 0; layer < 2; ++layer) {
    k_phaseA<<<dim3(256), dim3(256), 0, stream>>>(Ua, Va, Uo, Vo, flag, ma_ws, mo_ws, P16);
    k_phaseB<<<dim3(4096), dim3(256), 0, stream>>>(x16, P16, aspect, opinion);
    k_phaseC<<<dim3(4096, 2), dim3(256), 0, stream>>>(aspect, opinion, Wt16, zr_a, zr_o, xh_a, xh_o);
    k_transpose<<<dim3(384), dim3(256), 0, stream>>>(Ra, Ro, flag, Rt16);
    if (layer == 0) {
      k_scan<0><<<dim3(8), dim3(256), 0, stream>>>(zr_a, zr_o, xh_a, xh_o, Rt16, out);
      k_score<<<dim3(32768), dim3(256), 0, stream>>>(out, va, vo, flag, scores);
      k_softmax<<<dim3(128), dim3(256), 0, stream>>>(scores);
      k_ctx_m<<<dim3(128), dim3(1024), 0, stream>>>(scores, x_r, Ma, Mo, flag, ma_ws, mo_ws);
    } else {
      k_scan<1><<<dim3(8), dim3(256), 0, stream>>>(zr_a, zr_o, xh_a, xh_o, Rt16, out);
    }
  }
}

// Round 5
// 2345.606 us; speedup vs baseline: 1.2833x; 1.2833x over previous
//
#include <hip/hip_runtime.h>
#include <hip/hip_bf16.h>
#include <math.h>

#define B_  64
#define T_  1024
#define H_  256
#define K_  64
#define U_  128
#define U3_ 384

#define LOG2E_F 1.4426950408889634f

typedef unsigned short ushort_t;
typedef __attribute__((ext_vector_type(8))) short short8;
typedef __attribute__((ext_vector_type(8))) _Float16 half8;
typedef __attribute__((ext_vector_type(4))) _Float16 half4v;
typedef __attribute__((ext_vector_type(4))) float floatx4;

__device__ __forceinline__ float bf2f(ushort_t v) {
  unsigned int u = ((unsigned int)v) << 16;
  return __builtin_bit_cast(float, u);
}
__device__ __forceinline__ float h2f(ushort_t v) {
  return (float)__builtin_bit_cast(_Float16, v);
}
__device__ __forceinline__ ushort_t f2h(float f) {
  return __builtin_bit_cast(ushort_t, (_Float16)f);
}
__device__ __forceinline__ float ldf(const void* p, size_t i, int isf) {
  return isf ? ((const float*)p)[i] : bf2f(((const ushort_t*)p)[i]);
}
// native exp2 via builtin (compiler handles the trans hazard, no s_nop)
__device__ __forceinline__ float exp2_hw(float x) {
  return __builtin_amdgcn_exp2f(x);
}
// pack 2 f32 -> 2 f16 (RTZ) in one instr
__device__ __forceinline__ unsigned pk2h(float a, float b) {
  unsigned r;
  asm("v_cvt_pkrtz_f16_f32 %0, %1, %2" : "=v"(r) : "v"(a), "v"(b));
  return r;
}
// tanh via exp2: 1 - 2/(e^{2x}+1)
__device__ __forceinline__ float tanh_fast(float x) {
  float E = exp2_hw(2.f * LOG2E_F * x);
  return 1.f - 2.f * __builtin_amdgcn_rcpf(E + 1.f);
}

// ------------------------------------------------ dtype sniff: flag=1 if inputs are f32
__global__ void k_sniff(const ushort_t* __restrict__ xr, int* __restrict__ flag) {
  __shared__ int red[256];
  int tx = threadIdx.x;
  int hits = 0;
  for (int i = 0; i < 64; ++i) {
    ushort_t w = xr[tx + i * 256];
    int e = (w >> 7) & 0xff;
    hits += (e >= 0x70 && e <= 0x82) ? 1 : 0;
  }
  red[tx] = hits;
  __syncthreads();
  for (int off = 128; off > 0; off >>= 1) {
    if (tx < off) red[tx] += red[tx + off];
    __syncthreads();
  }
  if (tx == 0) flag[0] = (red[0] < 12288) ? 1 : 0;
}

// ------------------------------------------------ canonicalize x to f16 arena
__global__ __launch_bounds__(256) void k_canon_x(const void* __restrict__ xr,
                                                 const int* __restrict__ flag,
                                                 ushort_t* __restrict__ x16) {
  int tid = blockIdx.x * 256 + threadIdx.x;
  float v[8];
  if (*flag) {
    const float4* xf = (const float4*)xr;
    float4 a = xf[tid * 2], b = xf[tid * 2 + 1];
    v[0] = a.x; v[1] = a.y; v[2] = a.z; v[3] = a.w;
    v[4] = b.x; v[5] = b.y; v[6] = b.z; v[7] = b.w;
  } else {
    uint4 raw = ((const uint4*)xr)[tid];
    v[0] = bf2f((ushort_t)(raw.x & 0xffff)); v[1] = bf2f((ushort_t)(raw.x >> 16));
    v[2] = bf2f((ushort_t)(raw.y & 0xffff)); v[3] = bf2f((ushort_t)(raw.y >> 16));
    v[4] = bf2f((ushort_t)(raw.z & 0xffff)); v[5] = bf2f((ushort_t)(raw.z >> 16));
    v[6] = bf2f((ushort_t)(raw.w & 0xffff)); v[7] = bf2f((ushort_t)(raw.w >> 16));
  }
  uint4 o;
  o.x = (unsigned)f2h(v[0]) | ((unsigned)f2h(v[1]) << 16);
  o.y = (unsigned)f2h(v[2]) | ((unsigned)f2h(v[3]) << 16);
  o.z = (unsigned)f2h(v[4]) | ((unsigned)f2h(v[5]) << 16);
  o.w = (unsigned)f2h(v[6]) | ((unsigned)f2h(v[7]) << 16);
  ((uint4*)x16)[tid] = o;
}

// ------------------------------------------------ init m state
__global__ void k_init_m(const void* __restrict__ m0a, const void* __restrict__ m0o,
                         const int* __restrict__ flag,
                         float* __restrict__ ma_ws, float* __restrict__ mo_ws) {
  int b = blockIdx.x, tx = threadIdx.x, isf = *flag;
  ma_ws[b * H_ + tx] = ldf(m0a, tx, isf);
  mo_ws[b * H_ + tx] = ldf(m0o, tx, isf);
}

// ------------------------------------------------ Wt16[g][j][u] = W_g[u][j] * scale(j)
// scale = -log2e for z|r rows (j<256), +2*log2e for h rows (j>=256).
__global__ void k_transpose(const void* __restrict__ Wa, const void* __restrict__ Wo,
                            const int* __restrict__ flag, ushort_t* __restrict__ Wt16) {
  int bx = blockIdx.x, isf = *flag;
  int g = bx / 192;
  int i = (bx % 192) * 256 + threadIdx.x;  // i = j*128 + u
  const void* W = g ? Wo : Wa;
  int jj = i >> 7, u = i & 127;
  float sc = (jj < 256) ? -LOG2E_F : (2.f * LOG2E_F);
  Wt16[(size_t)g * (U3_ * U_) + i] = f2h(ldf(W, u * U3_ + jj, isf) * sc);
}

// ------------------------------------------------ Phase A: P16[b, g*64+k, h] = sum_j U[k,h,j] m[b,j]
__global__ __launch_bounds__(256) void k_phaseA(
    const void* __restrict__ Ua, const void* __restrict__ Va,
    const void* __restrict__ Uo, const void* __restrict__ Vo,
    const int* __restrict__ flag,
    const float* __restrict__ ma_ws, const float* __restrict__ mo_ws,
    ushort_t* __restrict__ P16) {
  int gk = blockIdx.x;
  int g = gk >> 6, k = gk & 63;
  const void* U = (g == 0) ? Ua : (g == 1) ? Va : (g == 2) ? Uo : Vo;
  const float* msrc = (g & 1) ? mo_ws : ma_ws;
  int tx = threadIdx.x;  // h
  int isf = *flag;
  __shared__ __align__(16) float m_l[64 * 128];
  float acc[64];
#pragma unroll
  for (int b = 0; b < 64; ++b) acc[b] = 0.f;
  size_t rowoff = ((size_t)k * H_ + tx) * H_;
  for (int pass = 0; pass < 2; ++pass) {
    for (int i = 0; i < 32; ++i) {
      int flat = tx + i * 256;
      m_l[flat] = msrc[(flat >> 7) * H_ + pass * 128 + (flat & 127)];
    }
    __syncthreads();
    for (int c = 0; c < 16; ++c) {
      float uv[8];
      if (isf) {
        const float* uf = (const float*)U + rowoff + pass * 128 + c * 8;
        float4 A = *(const float4*)uf;
        float4 Bv = *(const float4*)(uf + 4);
        uv[0] = A.x; uv[1] = A.y; uv[2] = A.z; uv[3] = A.w;
        uv[4] = Bv.x; uv[5] = Bv.y; uv[6] = Bv.z; uv[7] = Bv.w;
      } else {
        const ushort_t* ub = (const ushort_t*)U + rowoff + pass * 128 + c * 8;
        uint4 raw = *(const uint4*)ub;
        uv[0] = bf2f((ushort_t)(raw.x & 0xffff)); uv[1] = bf2f((ushort_t)(raw.x >> 16));
        uv[2] = bf2f((ushort_t)(raw.y & 0xffff)); uv[3] = bf2f((ushort_t)(raw.y >> 16));
        uv[4] = bf2f((ushort_t)(raw.z & 0xffff)); uv[5] = bf2f((ushort_t)(raw.z >> 16));
        uv[6] = bf2f((ushort_t)(raw.w & 0xffff)); uv[7] = bf2f((ushort_t)(raw.w >> 16));
      }
#pragma unroll
      for (int b = 0; b < 64; ++b) {
        const float* mr = &m_l[b * 128 + c * 8];
        float4 mA = *(const float4*)mr;
        float4 mB = *(const float4*)(mr + 4);
        float s = acc[b];
        s = fmaf(uv[0], mA.x, s); s = fmaf(uv[1], mA.y, s);
        s = fmaf(uv[2], mA.z, s); s = fmaf(uv[3], mA.w, s);
        s = fmaf(uv[4], mB.x, s); s = fmaf(uv[5], mB.y, s);
        s = fmaf(uv[6], mB.z, s); s = fmaf(uv[7], mB.w, s);
        acc[b] = s;
      }
    }
    __syncthreads();
  }
  size_t base = ((size_t)(g * 64 + k)) * H_ + tx;
#pragma unroll 4
  for (int b = 0; b < 64; ++b) P16[base + (size_t)b * (256 * H_)] = f2h(acc[b]);
}

// ------------------------------------------------ Phase B (MFMA f16): tanh(x[b]·P[b]^T)
__global__ __launch_bounds__(256) void k_phaseB(
    const ushort_t* __restrict__ x16, const ushort_t* __restrict__ P16,
    ushort_t* __restrict__ aspect, ushort_t* __restrict__ opinion) {
  int bx = blockIdx.x;          // 4096 = 64 b x 64 tt
  int b = bx >> 6, tt = bx & 63;
  int w = threadIdx.x >> 6;
  int lane = threadIdx.x & 63;
  int m = lane & 15, q = lane >> 4;
  const ushort_t* arow = x16 + ((size_t)(b * T_ + tt * 16 + m)) * H_ + q * 8;
  half8 af[8];
#pragma unroll
  for (int c = 0; c < 8; ++c)
    af[c] = __builtin_bit_cast(half8, *(const short8*)(arow + c * 32));
  const ushort_t* pbase = P16 + ((size_t)(b * 256 + m)) * H_ + q * 8;
#pragma unroll
  for (int s = 0; s < 4; ++s) {
    int ntile = s * 4 + w;
    const ushort_t* brow = pbase + (size_t)(ntile * 16) * H_;
    floatx4 acc = {0.f, 0.f, 0.f, 0.f}, acc2 = acc;
#pragma unroll
    for (int c = 0; c < 4; ++c) {
      half8 bf = __builtin_bit_cast(half8, *(const short8*)(brow + c * 32));
      acc = __builtin_amdgcn_mfma_f32_16x16x32_f16(af[c], bf, acc, 0, 0, 0);
      half8 bf2 = __builtin_bit_cast(half8, *(const short8*)(brow + (c + 4) * 32));
      acc2 = __builtin_amdgcn_mfma_f32_16x16x32_f16(af[c + 4], bf2, acc2, 0, 0, 0);
    }
    int n = ntile * 16 + m;
    ushort_t* dst;
    int nn;
    if (n < 128) { dst = aspect; nn = n; } else { dst = opinion; nn = n - 128; }
#pragma unroll
    for (int i = 0; i < 4; ++i) {
      int t = tt * 16 + q * 4 + i;
      dst[((size_t)(b * T_ + t)) * U_ + nn] = f2h(tanh_fast(acc[i] + acc2[i]));
    }
  }
}

// ------------------------------------------------ Phase C (MFMA f16): xw = seq @ Wt
// z|r cols interleaved per 4-col group so scan reads z+r as one uint4.
__global__ __launch_bounds__(256) void k_phaseC(
    const ushort_t* __restrict__ aspect, const ushort_t* __restrict__ opinion,
    const ushort_t* __restrict__ Wt16,
    ushort_t* __restrict__ zr_a, ushort_t* __restrict__ zr_o,
    ushort_t* __restrict__ xh_a, ushort_t* __restrict__ xh_o) {
  int g = blockIdx.y;
  const ushort_t* A = g ? opinion : aspect;
  const ushort_t* Bm = Wt16 + (size_t)g * (U3_ * U_);
  ushort_t* ZR = g ? zr_o : zr_a;
  ushort_t* XH = g ? xh_o : xh_a;
  int mt = blockIdx.x;
  int w = threadIdx.x >> 6;
  int lane = threadIdx.x & 63;
  int m = lane & 15, q = lane >> 4;
  const ushort_t* arow = A + ((size_t)(mt * 16 + m)) * U_ + q * 8;
  half8 af[4];
#pragma unroll
  for (int c = 0; c < 4; ++c)
    af[c] = __builtin_bit_cast(half8, *(const short8*)(arow + c * 32));
  const ushort_t* bbase = Bm + (size_t)m * U_ + q * 8;
#pragma unroll
  for (int s = 0; s < 6; ++s) {
    int nt = s * 4 + w;
    const ushort_t* brow = bbase + (size_t)(nt * 16) * U_;
    floatx4 acc = {0.f, 0.f, 0.f, 0.f};
#pragma unroll
    for (int c = 0; c < 4; ++c) {
      half8 bf = __builtin_bit_cast(half8, *(const short8*)(brow + c * 32));
      acc = __builtin_amdgcn_mfma_f32_16x16x32_f16(af[c], bf, acc, 0, 0, 0);
    }
    int col = nt * 16 + m;
    if (nt < 16) {
      int c2 = (col < 128) ? (((col >> 2) << 3) + (col & 3))
                           : ((((col - 128) >> 2) << 3) + 4 + (col & 3));
#pragma unroll
      for (int i = 0; i < 4; ++i) {
        int row = mt * 16 + q * 4 + i;
        ZR[(size_t)row * 256 + c2] = f2h(acc[i]);
      }
    } else {
#pragma unroll
      for (int i = 0; i < 4; ++i) {
        int row = mt * 16 + q * 4 + i;
        XH[(size_t)row * U_ + (col - 256)] = f2h(acc[i]);
      }
    }
  }
}

// ------------------------------------------------ GRU scan, MFMA-batched over b.
// Proven 8-wave structure (R3) + per-wave ROTATED k-slice order: wave w loads
// its Rt frags and reads h-frags starting at slice (w&3), so the 8 waves'
// initial ds_read bursts target different slices and each wave's first MFMA
// pair starts after ~1/4 of the LDS drain instead of all of it. Rotation is
// applied to data placement (af[gt][s] holds slice (w&3)^s), so all register
// indices stay compile-time (rule #20). Gate args pre-scaled (exp2 form).
template <int LAYER>
__global__ __launch_bounds__(512) void k_scan(
    const ushort_t* __restrict__ zr_a, const ushort_t* __restrict__ zr_o,
    const ushort_t* __restrict__ xh_a, const ushort_t* __restrict__ xh_o,
    const ushort_t* __restrict__ Rt16,
    float* __restrict__ out) {
  int g = blockIdx.x >> 2;
  int bb = (blockIdx.x & 3) << 4;
  int tid = threadIdx.x;
  int w = tid >> 6;
  int lane = tid & 63;
  int r = lane & 15;
  int q = lane >> 4;
  int b = bb + r;
  int j = (w << 4) + (q << 2);
  int ro = w & 3;  // rotation: slice index for static slot s is (ro ^ s)

  const ushort_t* zr = g ? zr_o : zr_a;
  const ushort_t* xh = g ? xh_o : xh_a;
  const ushort_t* Rt = Rt16 + (size_t)g * (U3_ * U_);

  // af[gt][s] = Rt rows [128*gt + 16w + r], k-slice (ro ^ s)
  half8 af[3][4];
#pragma unroll
  for (int gt = 0; gt < 3; ++gt) {
    size_t row = (size_t)(128 * gt + 16 * w + r) * U_;
#pragma unroll
    for (int s = 0; s < 4; ++s) {
      int ks = ro ^ s;
      af[gt][s] = __builtin_bit_cast(half8, *(const short8*)(Rt + row + ks * 32 + q * 8));
    }
  }

  __shared__ __align__(16) ushort_t hbuf[4096];  // 2 x 4KB frag buffers
  ((uint2*)hbuf)[tid] = (uint2){0u, 0u};         // zero buffer 0

  float hs0 = 0.f, hs1 = 0.f, hs2 = 0.f, hs3 = 0.f;

  const ushort_t* zp = zr + (size_t)b * (T_ * 256) + ((j >> 2) << 3);  // interleaved z|r
  const ushort_t* xp = xh + (size_t)b * (T_ * U_) + j;
  float* op = out + ((size_t)g * B_ * T_ + (size_t)b * T_) * U_ + j;

  uint4 zrA = *(const uint4*)zp;
  uint4 zrB = *(const uint4*)(zp + 256);
  uint2 hA = *(const uint2*)xp;
  uint2 hB = *(const uint2*)(xp + U_);
  float4 oA = make_float4(0.f, 0.f, 0.f, 0.f), oB = oA;
  if (LAYER) {
    oA = *(const float4*)op;
    oB = *(const float4*)(op + U_);
  }
  float4 pendE = make_float4(0.f, 0.f, 0.f, 0.f), pendO = pendE;

  int wofs = (w >> 1) * 512 + (r + 16 * (((w & 1) << 1) + (q >> 1))) * 8 + (q & 1) * 4;

  // rotated h-frag byte offsets (ushort units), static per slot
  int f0 = (ro ^ 0) * 512 + lane * 8;
  int f1 = (ro ^ 1) * 512 + lane * 8;
  int f2 = (ro ^ 2) * 512 + lane * 8;
  int f3 = (ro ^ 3) * 512 + lane * 8;

  __syncthreads();

  for (int t = 0; t < T_; t += 2) {
    // ===== even step t : read buf0, write buf1
    {
      half8 bf0 = __builtin_bit_cast(half8, *(const short8*)(&hbuf[f0]));
      half8 bf1 = __builtin_bit_cast(half8, *(const short8*)(&hbuf[f1]));
      half8 bf2 = __builtin_bit_cast(half8, *(const short8*)(&hbuf[f2]));
      half8 bf3 = __builtin_bit_cast(half8, *(const short8*)(&hbuf[f3]));
      if (t != 0) *(float4*)(op - U_) = pendO;  // store step t-1 in the read shadow
      int adv = (t + 2 < T_) ? 2 : 0;
      uint4 pzr = *(const uint4*)(zp + adv * 256);
      uint2 ph = *(const uint2*)(xp + adv * U_);
      float4 po;
      if (LAYER) po = *(const float4*)(op + adv * U_);

      floatx4 a0 = {0.f, 0.f, 0.f, 0.f}, a1 = a0, a2 = a0, c0 = a0, c1 = a0, c2 = a0;
      a0 = __builtin_amdgcn_mfma_f32_16x16x32_f16(af[0][0], bf0, a0, 0, 0, 0);
      a1 = __builtin_amdgcn_mfma_f32_16x16x32_f16(af[1][0], bf0, a1, 0, 0, 0);
      a2 = __builtin_amdgcn_mfma_f32_16x16x32_f16(af[2][0], bf0, a2, 0, 0, 0);
      c0 = __builtin_amdgcn_mfma_f32_16x16x32_f16(af[0][2], bf2, c0, 0, 0, 0);
      c1 = __builtin_amdgcn_mfma_f32_16x16x32_f16(af[1][2], bf2, c1, 0, 0, 0);
      c2 = __builtin_amdgcn_mfma_f32_16x16x32_f16(af[2][2], bf2, c2, 0, 0, 0);
      a0 = __builtin_amdgcn_mfma_f32_16x16x32_f16(af[0][1], bf1, a0, 0, 0, 0);
      a1 = __builtin_amdgcn_mfma_f32_16x16x32_f16(af[1][1], bf1, a1, 0, 0, 0);
      a2 = __builtin_amdgcn_mfma_f32_16x16x32_f16(af[2][1], bf1, a2, 0, 0, 0);
      c0 = __builtin_amdgcn_mfma_f32_16x16x32_f16(af[0][3], bf3, c0, 0, 0, 0);
      c1 = __builtin_amdgcn_mfma_f32_16x16x32_f16(af[1][3], bf3, c1, 0, 0, 0);
      c2 = __builtin_amdgcn_mfma_f32_16x16x32_f16(af[2][3], bf3, c2, 0, 0, 0);

      half8 zr8 = __builtin_bit_cast(half8, zrA);
      half4v xh4 = __builtin_bit_cast(half4v, hA);
      float hp[4] = {hs0, hs1, hs2, hs3};
      float hn[4];
#pragma unroll
      for (int i = 0; i < 4; ++i) {
        float zq = (float)zr8[i] + (a0[i] + c0[i]);       // = -log2e*(xz+hz)
        float rq = (float)zr8[4 + i] + (a1[i] + c1[i]);
        float z = __builtin_amdgcn_rcpf(1.f + exp2_hw(zq));
        float rr = __builtin_amdgcn_rcpf(1.f + exp2_hw(rq));
        float y2 = fmaf(rr, a2[i] + c2[i], (float)xh4[i]); // = 2*log2e*y
        float th = fmaf(-2.f, __builtin_amdgcn_rcpf(exp2_hw(y2) + 1.f), 1.f);
        hn[i] = fmaf(z, hp[i] - th, th);
      }
      hs0 = hn[0]; hs1 = hn[1]; hs2 = hn[2]; hs3 = hn[3];
      pendE.x = LAYER ? (oA.x + hn[0]) : hn[0];
      pendE.y = LAYER ? (oA.y + hn[1]) : hn[1];
      pendE.z = LAYER ? (oA.z + hn[2]) : hn[2];
      pendE.w = LAYER ? (oA.w + hn[3]) : hn[3];
      uint2 wv;
      wv.x = pk2h(hn[0], hn[1]);
      wv.y = pk2h(hn[2], hn[3]);
      *(uint2*)(&hbuf[2048 + wofs]) = wv;
      zrA = pzr; hA = ph;
      if (LAYER) oA = po;
    }
    asm volatile("s_waitcnt lgkmcnt(0)" ::: "memory");
    __builtin_amdgcn_s_barrier();
    __builtin_amdgcn_sched_barrier(0);
    // ===== odd step t+1 : read buf1, write buf0
    {
      half8 bf0 = __builtin_bit_cast(half8, *(const short8*)(&hbuf[2048 + f0]));
      half8 bf1 = __builtin_bit_cast(half8, *(const short8*)(&hbuf[2048 + f1]));
      half8 bf2 = __builtin_bit_cast(half8, *(const short8*)(&hbuf[2048 + f2]));
      half8 bf3 = __builtin_bit_cast(half8, *(const short8*)(&hbuf[2048 + f3]));
      *(float4*)op = pendE;  // store step t in the read shadow
      int adv = (t + 3 < T_) ? 2 : 0;
      uint4 pzr = *(const uint4*)(zp + 256 + adv * 256);
      uint2 ph = *(const uint2*)(xp + U_ + adv * U_);
      float4 po;
      if (LAYER) po = *(const float4*)(op + U_ + adv * U_);

      floatx4 a0 = {0.f, 0.f, 0.f, 0.f}, a1 = a0, a2 = a0, c0 = a0, c1 = a0, c2 = a0;
      a0 = __builtin_amdgcn_mfma_f32_16x16x32_f16(af[0][0], bf0, a0, 0, 0, 0);
      a1 = __builtin_amdgcn_mfma_f32_16x16x32_f16(af[1][0], bf0, a1, 0, 0, 0);
      a2 = __builtin_amdgcn_mfma_f32_16x16x32_f16(af[2][0], bf0, a2, 0, 0, 0);
      c0 = __builtin_amdgcn_mfma_f32_16x16x32_f16(af[0][2], bf2, c0, 0, 0, 0);
      c1 = __builtin_amdgcn_mfma_f32_16x16x32_f16(af[1][2], bf2, c1, 0, 0, 0);
      c2 = __builtin_amdgcn_mfma_f32_16x16x32_f16(af[2][2], bf2, c2, 0, 0, 0);
      a0 = __builtin_amdgcn_mfma_f32_16x16x32_f16(af[0][1], bf1, a0, 0, 0, 0);
      a1 = __builtin_amdgcn_mfma_f32_16x16x32_f16(af[1][1], bf1, a1, 0, 0, 0);
      a2 = __builtin_amdgcn_mfma_f32_16x16x32_f16(af[2][1], bf1, a2, 0, 0, 0);
      c0 = __builtin_amdgcn_mfma_f32_16x16x32_f16(af[0][3], bf3, c0, 0, 0, 0);
      c1 = __builtin_amdgcn_mfma_f32_16x16x32_f16(af[1][3], bf3, c1, 0, 0, 0);
      c2 = __builtin_amdgcn_mfma_f32_16x16x32_f16(af[2][3], bf3, c2, 0, 0, 0);

      half8 zr8 = __builtin_bit_cast(half8, zrB);
      half4v xh4 = __builtin_bit_cast(half4v, hB);
      float hp[4] = {hs0, hs1, hs2, hs3};
      float hn[4];
#pragma unroll
      for (int i = 0; i < 4; ++i) {
        float zq = (float)zr8[i] + (a0[i] + c0[i]);
        float rq = (float)zr8[4 + i] + (a1[i] + c1[i]);
        float z = __builtin_amdgcn_rcpf(1.f + exp2_hw(zq));
        float rr = __builtin_amdgcn_rcpf(1.f + exp2_hw(rq));
        float y2 = fmaf(rr, a2[i] + c2[i], (float)xh4[i]);
        float th = fmaf(-2.f, __builtin_amdgcn_rcpf(exp2_hw(y2) + 1.f), 1.f);
        hn[i] = fmaf(z, hp[i] - th, th);
      }
      hs0 = hn[0]; hs1 = hn[1]; hs2 = hn[2]; hs3 = hn[3];
      pendO.x = LAYER ? (oB.x + hn[0]) : hn[0];
      pendO.y = LAYER ? (oB.y + hn[1]) : hn[1];
      pendO.z = LAYER ? (oB.z + hn[2]) : hn[2];
      pendO.w = LAYER ? (oB.w + hn[3]) : hn[3];
      uint2 wv;
      wv.x = pk2h(hn[0], hn[1]);
      wv.y = pk2h(hn[2], hn[3]);
      *(uint2*)(&hbuf[0 + wofs]) = wv;
      zrB = pzr; hB = ph;
      if (LAYER) oB = po;
    }
    asm volatile("s_waitcnt lgkmcnt(0)" ::: "memory");
    __builtin_amdgcn_s_barrier();
    __builtin_amdgcn_sched_barrier(0);
    zp += 512; xp += 2 * U_; op += 2 * U_;
  }
  *(float4*)(op - U_) = pendO;  // final step T-1
}

// ------------------------------------------------ scores[g,b,t] = ra[b,t,:]·v
__global__ void k_score(const float* __restrict__ out, const void* __restrict__ va,
                        const void* __restrict__ vo, const int* __restrict__ flag,
                        float* __restrict__ scores) {
  int wave = threadIdx.x >> 6, lane = threadIdx.x & 63;
  int pair = blockIdx.x * 4 + wave;
  int g = pair >> 16;
  int bt = pair & 65535;
  int isf = *flag;
  const void* v = g ? vo : va;
  const float* o = out + ((size_t)g * (B_ * T_) + bt) * U_ + lane * 2;
  float s = o[0] * ldf(v, lane * 2, isf) + o[1] * ldf(v, lane * 2 + 1, isf);
#pragma unroll
  for (int off = 32; off > 0; off >>= 1) s += __shfl_down(s, off, 64);
  if (lane == 0) scores[pair] = s;
}

// ------------------------------------------------ softmax over T, in place
__global__ void k_softmax(float* __restrict__ scores) {
  int row = blockIdx.x;
  float* s = scores + (size_t)row * T_;
  int tx = threadIdx.x;
  __shared__ float red[256];
  float v[4];
  float mx = -1e30f;
#pragma unroll
  for (int i = 0; i < 4; ++i) { v[i] = s[tx + i * 256]; mx = fmaxf(mx, v[i]); }
  red[tx] = mx;
  __syncthreads();
  for (int off = 128; off > 0; off >>= 1) {
    if (tx < off) red[tx] = fmaxf(red[tx], red[tx + off]);
    __syncthreads();
  }
  float M = red[0];
  __syncthreads();
  float sm = 0.f;
#pragma unroll
  for (int i = 0; i < 4; ++i) { v[i] = expf(v[i] - M); sm += v[i]; }
  red[tx] = sm;
  __syncthreads();
  for (int off = 128; off > 0; off >>= 1) {
    if (tx < off) red[tx] += red[tx + off];
    __syncthreads();
  }
  float inv = 1.f / red[0];
#pragma unroll
  for (int i = 0; i < 4; ++i) s[tx + i * 256] = v[i] * inv;
}

// ------------------------------------------------ m = tanh(m@M) + alpha^T x  (4-way t-parallel)
__global__ __launch_bounds__(1024) void k_ctx_m(const float* __restrict__ alpha,
                                                const void* __restrict__ x,
                                                const void* __restrict__ Ma,
                                                const void* __restrict__ Mo,
                                                const int* __restrict__ flag,
                                                float* __restrict__ ma_ws,
                                                float* __restrict__ mo_ws) {
  int g = blockIdx.x >> 6, b = blockIdx.x & 63;
  int isf = *flag;
  int tid = threadIdx.x;
  int tx = tid & 255;
  int ty = tid >> 8;
  __shared__ float a_l[1024];
  __shared__ float m_l[256];
  __shared__ float pA[4][256];
  __shared__ float pB[4][256];
  const float* al = alpha + ((size_t)g * B_ + b) * T_;
  a_l[tid] = al[tid];
  if (ty == 0) m_l[tx] = (g ? mo_ws : ma_ws)[b * H_ + tx];
  __syncthreads();
  const void* Mm = g ? Mo : Ma;
  float acc = 0.f;
#pragma unroll 4
  for (int t0 = 0; t0 < 256; ++t0) {
    int t = ty * 256 + t0;
    acc = fmaf(a_l[t], ldf(x, (size_t)(b * T_ + t) * H_ + tx, isf), acc);
  }
  float acc2 = 0.f;
#pragma unroll 4
  for (int c = 0; c < 64; ++c) {
    int jj = ty * 64 + c;
    acc2 = fmaf(m_l[jj], ldf(Mm, (size_t)jj * 256 + tx, isf), acc2);
  }
  pA[ty][tx] = acc;
  pB[ty][tx] = acc2;
  __syncthreads();
  if (ty == 0) {
    float A = pA[0][tx] + pA[1][tx] + pA[2][tx] + pA[3][tx];
    float Bv = pB[0][tx] + pB[1][tx] + pB[2][tx] + pB[3][tx];
    float* m_ws = g ? mo_ws : ma_ws;
    m_ws[b * H_ + tx] = tanhf(Bv) + A;
  }
}

// ------------------------------------------------ launch
extern "C" void kernel_launch(void* const* d_in, const int* in_sizes, int n_in,
                              void* d_out, int out_size, void* d_ws, size_t ws_size,
                              hipStream_t stream) {
  const void* x_r = d_in[0];
  const void* m0a = d_in[1];
  const void* m0o = d_in[2];
  const void* Ua  = d_in[3];
  const void* Uo  = d_in[4];
  const void* Va  = d_in[5];
  const void* Vo  = d_in[6];
  const void* Ma  = d_in[7];
  const void* Mo  = d_in[8];
  const void* va  = d_in[9];
  const void* vo  = d_in[10];
  const void* Wa  = d_in[11];
  const void* Ra  = d_in[12];
  const void* Wo  = d_in[13];
  const void* Ro  = d_in[14];
  float* out = (float*)d_out;

  char* ws = (char*)d_ws;
  int*      flag    = (int*)(ws + 0);                // 1 KB pad
  float*    ma_ws   = (float*)(ws + 1024);           // 64 KB
  float*    mo_ws   = (float*)(ws + 66560);          // 64 KB
  ushort_t* Wt16    = (ushort_t*)(ws + 132096);      // 192 KB [2,384,128] f16, pre-scaled
  ushort_t* x16     = (ushort_t*)(ws + 328704);      // 32 MB  [64,1024,256] f16
  ushort_t* P16     = (ushort_t*)(ws + 33883136);    // 8 MB   [64,256,256] f16
  float*    scores  = (float*)(ws + 33883136);       // ALIAS: P16 dead while scores live
  ushort_t* Rt16    = (ushort_t*)(ws + 33883136 + 1048576);  // ALIAS in P16 region @+1MB
  ushort_t* aspect  = (ushort_t*)(ws + 42271744);    // 16 MB
  ushort_t* opinion = (ushort_t*)(ws + 59048960);    // 16 MB
  ushort_t* zr_a    = (ushort_t*)(ws + 75826176);    // 32 MB (z|r interleaved per 4-col)
  ushort_t* zr_o    = (ushort_t*)(ws + 109380608);   // 32 MB
  ushort_t* xh_a    = (ushort_t*)(ws + 142935040);   // 16 MB
  ushort_t* xh_o    = (ushort_t*)(ws + 159712256);   // 16 MB -> total 176,489,472 B

  if (ws_size < 176489472ULL) return;

  k_sniff<<<dim3(1), dim3(256), 0, stream>>>((const ushort_t*)x_r, flag);
  k_canon_x<<<dim3(8192), dim3(256), 0, stream>>>(x_r, flag, x16);
  k_init_m<<<dim3(64), dim3(256), 0, stream>>>(m0a, m0o, flag, ma_ws, mo_ws);
  k_transpose<<<dim3(384), dim3(256), 0, stream>>>(Wa, Wo, flag, Wt16);

  for (int layer = 0; layer < 2; ++layer) {
    k_phaseA<<<dim3(256), dim3(256), 0, stream>>>(Ua, Va, Uo, Vo, flag, ma_ws, mo_ws, P16);
    k_phaseB<<<dim3(4096), dim3(256), 0, stream>>>(x16, P16, aspect, opinion);
    k_phaseC<<<dim3(4096, 2), dim3(256), 0, stream>>>(aspect, opinion, Wt16, zr_a, zr_o, xh_a, xh_o);
    k_transpose<<<dim3(384), dim3(256), 0, stream>>>(Ra, Ro, flag, Rt16);
    if (layer == 0) {
      k_scan<0><<<dim3(8), dim3(512), 0, stream>>>(zr_a, zr_o, xh_a, xh_o, Rt16, out);
      k_score<<<dim3(32768), dim3(256), 0, stream>>>(out, va, vo, flag, scores);
      k_softmax<<<dim3(128), dim3(256), 0, stream>>>(scores);
      k_ctx_m<<<dim3(128), dim3(1024), 0, stream>>>(scores, x_r, Ma, Mo, flag, ma_ws, mo_ws);
    } else {
      k_scan<1><<<dim3(8), dim3(512), 0, stream>>>(zr_a, zr_o, xh_a, xh_o, Rt16, out);
    }
  }
}